// Round 5
// baseline (248.145 us; speedup 1.0000x reference)
//
#include <hip/hip_runtime.h>

// J-loss via MFMA: T[b,i,k] = sum_p pred[b,i,p] * onehot(target[b,p]==k)
// j[b] = -sum_{i!=k} log(0.5 + 0.5*(T[b,i,i]/n[b,i] - T[b,i,k]/n[b,k]))
//
// R4 post-mortem: LDS staging regressed; real delta was 4x global atomics
// (4608 blocks x 1024 atomicAdds into 32KB -> serialization). R5: back to
// R3 direct loads; flush via PLAIN stores of per-block partials into d_ws
// (no atomics anywhere), fused reduce+final stage-2 kernel; memset deleted.

#define BB 8
#define CC 32
#define HW 147456                 // 384*384
#define CHUNK_PX 1024             // pixels per block (4 waves x 256 px)
#define NCHUNK (HW / CHUNK_PX)    // 144
#define PART (CC * CC + CC)       // 1056 floats per block partial (T + cnt)

typedef __attribute__((ext_vector_type(8))) short short8;
typedef __attribute__((ext_vector_type(4))) float float4v;
typedef __attribute__((ext_vector_type(4))) unsigned uint4v;

// pack trunc-bf16(lo), trunc-bf16(hi) into one dword: 1 v_perm_b32
__device__ __forceinline__ unsigned pk(float lo, float hi) {
    return __builtin_amdgcn_perm(__float_as_uint(hi), __float_as_uint(lo), 0x07060302u);
}
// packed pair of one-hot bf16 values for classes (ta,tb) vs m
__device__ __forceinline__ unsigned oh2(int ta, int tb, int m) {
    return (ta == m ? 0x3F80u : 0u) | (tb == m ? 0x3F800000u : 0u);
}

__global__ __launch_bounds__(256, 4) void jloss_mfma(
    const float* __restrict__ pred,    // [B][C][HW]
    const int*   __restrict__ target,  // [B][HW]
    float*       __restrict__ P)       // [B*NCHUNK][PART] partials
{
    const int tid  = threadIdx.x;
    const int w    = tid >> 6;         // wave 0..3
    const int l    = tid & 63;
    const int quad = l >> 4;
    const int m    = l & 15;
    const int blk  = blockIdx.x;
    const int b    = blk / NCHUNK;
    const int chunk= blk % NCHUNK;

    const long pb_wave = (long)chunk * CHUNK_PX + w * 256;
    const float* predb = pred + (long)b * CC * HW;
    const int*   tgtb  = target + (long)b * HW;

    float4v acc00 = {0,0,0,0}, acc01 = {0,0,0,0};
    float4v acc10 = {0,0,0,0}, acc11 = {0,0,0,0};
    float4v accc0 = {0,0,0,0}, accc1 = {0,0,0,0};   // counts: ones . B
    const short8 ONES = {0x3F80,0x3F80,0x3F80,0x3F80,0x3F80,0x3F80,0x3F80,0x3F80};

    #pragma unroll 2
    for (int ks = 0; ks < 8; ++ks) {   // 8 K-steps of 32 pixels
        const long po = pb_wave + ks * 32 + quad * 8;
        const float* p0 = predb + (long)m * HW + po;   // channel m
        const float* p1 = p0 + (long)16 * HW;          // channel m+16
        const float4 a0l = *(const float4*)p0;
        const float4 a0h = *(const float4*)(p0 + 4);
        const float4 a1l = *(const float4*)p1;
        const float4 a1h = *(const float4*)(p1 + 4);
        const int4 t0 = *(const int4*)(tgtb + po);
        const int4 t1 = *(const int4*)(tgtb + po + 4);

        union { short8 s; uint4v u; } A0, A1, B0, B1;
        A0.u[0] = pk(a0l.x, a0l.y); A0.u[1] = pk(a0l.z, a0l.w);
        A0.u[2] = pk(a0h.x, a0h.y); A0.u[3] = pk(a0h.z, a0h.w);
        A1.u[0] = pk(a1l.x, a1l.y); A1.u[1] = pk(a1l.z, a1l.w);
        A1.u[2] = pk(a1h.x, a1h.y); A1.u[3] = pk(a1h.z, a1h.w);
        B0.u[0] = oh2(t0.x, t0.y, m);      B0.u[1] = oh2(t0.z, t0.w, m);
        B0.u[2] = oh2(t1.x, t1.y, m);      B0.u[3] = oh2(t1.z, t1.w, m);
        const int m16 = m + 16;
        B1.u[0] = oh2(t0.x, t0.y, m16);    B1.u[1] = oh2(t0.z, t0.w, m16);
        B1.u[2] = oh2(t1.x, t1.y, m16);    B1.u[3] = oh2(t1.z, t1.w, m16);

        acc00 = __builtin_amdgcn_mfma_f32_16x16x32_bf16(A0.s, B0.s, acc00, 0, 0, 0);
        acc01 = __builtin_amdgcn_mfma_f32_16x16x32_bf16(A0.s, B1.s, acc01, 0, 0, 0);
        acc10 = __builtin_amdgcn_mfma_f32_16x16x32_bf16(A1.s, B0.s, acc10, 0, 0, 0);
        acc11 = __builtin_amdgcn_mfma_f32_16x16x32_bf16(A1.s, B1.s, acc11, 0, 0, 0);
        accc0 = __builtin_amdgcn_mfma_f32_16x16x32_bf16(ONES, B0.s, accc0, 0, 0, 0);
        accc1 = __builtin_amdgcn_mfma_f32_16x16x32_bf16(ONES, B1.s, accc1, 0, 0, 0);
    }

    // cross-wave reduce in LDS, then PLAIN coalesced stores of the partial
    __shared__ float red[4][CC][CC];   // 16 KB
    __shared__ float redc[4][CC];
    #pragma unroll
    for (int r = 0; r < 4; ++r) {      // C layout: row=quad*4+r, col=m (m89-verified)
        red[w][quad*4 + r     ][m     ] = acc00[r];
        red[w][quad*4 + r     ][m + 16] = acc01[r];
        red[w][quad*4 + r + 16][m     ] = acc10[r];
        red[w][quad*4 + r + 16][m + 16] = acc11[r];
    }
    if (quad == 0) {                   // counts: every row of accc is count[col]
        redc[w][m]      = accc0[0];
        redc[w][m + 16] = accc1[0];
    }
    __syncthreads();

    float* Pb = P + (long)blk * PART;
    const float* rp = &red[0][0][0];
    #pragma unroll
    for (int j = tid; j < CC * CC; j += 256)
        Pb[j] = rp[j] + rp[1024 + j] + rp[2048 + j] + rp[3072 + j];
    if (tid < CC)
        Pb[CC * CC + tid] = redc[0][tid] + redc[1][tid] + redc[2][tid] + redc[3][tid];
}

__global__ __launch_bounds__(256) void jloss_final(
    const float* __restrict__ P,       // [B*NCHUNK][PART]
    float*       __restrict__ out)
{
    const int b   = blockIdx.x;
    const int tid = threadIdx.x;
    __shared__ float Tb[CC * CC];
    __shared__ float cb[CC];
    __shared__ float diag_s[CC];
    __shared__ float inv_n[CC];
    __shared__ float wsum[4];

    // reduce 144 chunk-partials (coalesced: consecutive lanes -> consecutive j)
    const float* Pb = P + (long)b * NCHUNK * PART;
    for (int j = tid; j < PART; j += 256) {
        float s = 0.0f;
        for (int c = 0; c < NCHUNK; ++c) s += Pb[(long)c * PART + j];
        if (j < CC * CC) Tb[j] = s; else cb[j - CC * CC] = s;
    }
    __syncthreads();

    if (tid < CC) {
        const float inv = 1.0f / cb[tid];
        inv_n[tid]  = inv;
        diag_s[tid] = Tb[tid * CC + tid] * inv;
    }
    __syncthreads();

    float sum = 0.0f;
    for (int idx = tid; idx < CC * CC; idx += 256) {
        const int i = idx >> 5;
        const int k = idx & 31;
        if (i != k) {
            const float S = Tb[idx] * inv_n[k];
            sum += logf(0.5f + 0.5f * (diag_s[i] - S));
        }
    }
    #pragma unroll
    for (int off = 32; off > 0; off >>= 1) sum += __shfl_down(sum, off, 64);
    if ((tid & 63) == 0) wsum[tid >> 6] = sum;
    __syncthreads();
    if (tid == 0) out[b] = -(wsum[0] + wsum[1] + wsum[2] + wsum[3]);
}

extern "C" void kernel_launch(void* const* d_in, const int* in_sizes, int n_in,
                              void* d_out, int out_size, void* d_ws, size_t ws_size,
                              hipStream_t stream) {
    const float* pred   = (const float*)d_in[0];
    const int*   target = (const int*)d_in[1];
    float* out = (float*)d_out;
    float* P   = (float*)d_ws;    // BB*NCHUNK*PART floats = 4.87 MB, fully written

    jloss_mfma <<<BB * NCHUNK, 256, 0, stream>>>(pred, target, P);
    jloss_final<<<BB, 256, 0, stream>>>(P, out);
}

// Round 6
// 229.584 us; speedup vs baseline: 1.0808x; 1.0808x over previous
//
#include <hip/hip_runtime.h>

// J-loss via MFMA: T[b,i,k] = sum_p pred[b,i,p] * onehot(target[b,p]==k)
// j[b] = -sum_{i!=k} log(0.5 + 0.5*(T[b,i,i]/n[b,i] - T[b,i,k]/n[b,k]))
//
// R5 post-mortem: 8-block stage-2 reduce was latency-bound (+28us); R3's
// atomics were cheap. Real mfma limiter: A-load gather (32 half-used lines
// per instr) starves MLP (~2 TB/s). R6: global_load_lds staging (full-line
// 1KB-contiguous async, R4-style) + plain partial stores (no atomics,
// R5-style) + PARALLEL stage-2 (33 blocks, 1 thread per (b,j)).

#define BB 8
#define CC 32
#define HW 147456                 // 384*384
#define CHUNK_PX 1024             // pixels per block (4 sub-tiles of 256)
#define SUB_PX 256
#define NCHUNK (HW / CHUNK_PX)    // 144
#define STRIDE 258                // LDS row stride (floats)
#define PART (CC * CC + CC)       // 1056 floats per partial

typedef __attribute__((ext_vector_type(8))) short short8;
typedef __attribute__((ext_vector_type(4))) float float4v;
typedef __attribute__((ext_vector_type(4))) unsigned uint4v;

__device__ __forceinline__ unsigned pk(float lo, float hi) {
    return __builtin_amdgcn_perm(__float_as_uint(hi), __float_as_uint(lo), 0x07060302u);
}
__device__ __forceinline__ unsigned oh2(int ta, int tb, int m) {
    return (ta == m ? 0x3F80u : 0u) | (tb == m ? 0x3F800000u : 0u);
}

__global__ __launch_bounds__(256, 4) void jloss_mfma(
    const float* __restrict__ pred,    // [B][C][HW]
    const int*   __restrict__ target,  // [B][HW]
    float*       __restrict__ P)       // [B*NCHUNK][PART] partials
{
    __shared__ float tile[CC * STRIDE];   // 33 KB, reused for reduction

    const int tid  = threadIdx.x;
    const int w    = tid >> 6;
    const int l    = tid & 63;
    const int quad = l >> 4;
    const int m    = l & 15;
    const int blk  = blockIdx.x;
    const int b    = blk / NCHUNK;
    const int chunk= blk % NCHUNK;

    const long px0 = (long)chunk * CHUNK_PX;
    const float* predb = pred + (long)b * CC * HW;
    const int*   tgtb  = target + (long)b * HW;

    float4v acc00 = {0,0,0,0}, acc01 = {0,0,0,0};
    float4v acc10 = {0,0,0,0}, acc11 = {0,0,0,0};
    float4v accc0 = {0,0,0,0}, accc1 = {0,0,0,0};
    const short8 ONES = {0x3F80,0x3F80,0x3F80,0x3F80,0x3F80,0x3F80,0x3F80,0x3F80};

    for (int st = 0; st < 4; ++st) {
        const long pxs = px0 + st * SUB_PX;

        // ---- stage: wave w async-copies channel rows 8w..8w+7 (1 KB each) ----
        #pragma unroll
        for (int r = 0; r < 8; ++r) {
            const int c = w * 8 + r;
            const float* gp = predb + (long)c * HW + pxs + l * 4;
            __builtin_amdgcn_global_load_lds(
                (const __attribute__((address_space(1))) void*)gp,
                (__attribute__((address_space(3))) void*)&tile[c * STRIDE + l * 4],
                16, 0, 0);
        }
        // prefetch targets for both K-steps (latency hides under staging)
        const int base0 = (w * 2    ) * 32 + quad * 8;
        const int base1 = (w * 2 + 1) * 32 + quad * 8;
        const int4 t0a = *(const int4*)(tgtb + pxs + base0);
        const int4 t0b = *(const int4*)(tgtb + pxs + base0 + 4);
        const int4 t1a = *(const int4*)(tgtb + pxs + base1);
        const int4 t1b = *(const int4*)(tgtb + pxs + base1 + 4);
        __syncthreads();   // vmcnt(0) drain: staging + target loads complete

        // ---- compute: wave w owns K-steps {2w, 2w+1} of this sub-tile ----
        #pragma unroll
        for (int kk = 0; kk < 2; ++kk) {
            const int base = kk ? base1 : base0;
            const int4 ta = kk ? t1a : t0a;
            const int4 tb = kk ? t1b : t0b;
            const float2* r0 = (const float2*)&tile[m * STRIDE + base];
            const float2* r1 = (const float2*)&tile[(m + 16) * STRIDE + base];
            const float2 x0 = r0[0], x1 = r0[1], x2 = r0[2], x3 = r0[3];
            const float2 y0 = r1[0], y1 = r1[1], y2 = r1[2], y3 = r1[3];

            union { short8 s; uint4v u; } A0, A1, B0, B1;
            A0.u[0] = pk(x0.x, x0.y); A0.u[1] = pk(x1.x, x1.y);
            A0.u[2] = pk(x2.x, x2.y); A0.u[3] = pk(x3.x, x3.y);
            A1.u[0] = pk(y0.x, y0.y); A1.u[1] = pk(y1.x, y1.y);
            A1.u[2] = pk(y2.x, y2.y); A1.u[3] = pk(y3.x, y3.y);
            B0.u[0] = oh2(ta.x, ta.y, m);   B0.u[1] = oh2(ta.z, ta.w, m);
            B0.u[2] = oh2(tb.x, tb.y, m);   B0.u[3] = oh2(tb.z, tb.w, m);
            const int m16 = m + 16;
            B1.u[0] = oh2(ta.x, ta.y, m16); B1.u[1] = oh2(ta.z, ta.w, m16);
            B1.u[2] = oh2(tb.x, tb.y, m16); B1.u[3] = oh2(tb.z, tb.w, m16);

            acc00 = __builtin_amdgcn_mfma_f32_16x16x32_bf16(A0.s, B0.s, acc00, 0, 0, 0);
            acc01 = __builtin_amdgcn_mfma_f32_16x16x32_bf16(A0.s, B1.s, acc01, 0, 0, 0);
            acc10 = __builtin_amdgcn_mfma_f32_16x16x32_bf16(A1.s, B0.s, acc10, 0, 0, 0);
            acc11 = __builtin_amdgcn_mfma_f32_16x16x32_bf16(A1.s, B1.s, acc11, 0, 0, 0);
            accc0 = __builtin_amdgcn_mfma_f32_16x16x32_bf16(ONES, B0.s, accc0, 0, 0, 0);
            accc1 = __builtin_amdgcn_mfma_f32_16x16x32_bf16(ONES, B1.s, accc1, 0, 0, 0);
        }
        __syncthreads();   // tile reads done before restage / reuse
    }

    // ---- cross-wave reduce (tile reused), then PLAIN coalesced stores ----
    float (*red)[CC][CC] = (float (*)[CC][CC])tile;   // 16 KB
    float* redc = tile + 4 * CC * CC;                 // [4][32]
    #pragma unroll
    for (int r = 0; r < 4; ++r) {      // C layout: row=quad*4+r, col=m (m89-verified)
        red[w][quad*4 + r     ][m     ] = acc00[r];
        red[w][quad*4 + r     ][m + 16] = acc01[r];
        red[w][quad*4 + r + 16][m     ] = acc10[r];
        red[w][quad*4 + r + 16][m + 16] = acc11[r];
    }
    if (quad == 0) {
        redc[w * CC + m]      = accc0[0];
        redc[w * CC + m + 16] = accc1[0];
    }
    __syncthreads();

    float* Pb = P + (long)blk * PART;
    const float* rp = &red[0][0][0];
    #pragma unroll
    for (int j = tid; j < CC * CC; j += 256)
        Pb[j] = rp[j] + rp[1024 + j] + rp[2048 + j] + rp[3072 + j];
    if (tid < CC)
        Pb[CC * CC + tid] = redc[tid] + redc[CC + tid] + redc[2*CC + tid] + redc[3*CC + tid];
}

// stage-2a: one thread per (b,j) — 33 blocks x 256 = 8448 = BB*PART exactly
__global__ __launch_bounds__(256) void jloss_reduce(
    const float* __restrict__ P,       // [B*NCHUNK][PART]
    float*       __restrict__ Tn)      // [B][PART]
{
    const int gid = blockIdx.x * 256 + threadIdx.x;
    const int b   = gid / PART;
    const int j   = gid % PART;
    const float* Pb = P + (long)b * NCHUNK * PART + j;
    float s = 0.0f;
    #pragma unroll 8
    for (int c = 0; c < NCHUNK; ++c) s += Pb[(long)c * PART];
    Tn[gid] = s;
}

__global__ __launch_bounds__(256) void jloss_final(
    const float* __restrict__ Tn,      // [B][PART]
    float*       __restrict__ out)
{
    const int b   = blockIdx.x;
    const int tid = threadIdx.x;
    __shared__ float diag_s[CC];
    __shared__ float inv_n[CC];
    __shared__ float wsum[4];

    const float* Tb = Tn + (long)b * PART;
    const float* cb = Tb + CC * CC;

    if (tid < CC) {
        const float inv = 1.0f / cb[tid];
        inv_n[tid]  = inv;
        diag_s[tid] = Tb[tid * CC + tid] * inv;
    }
    __syncthreads();

    float sum = 0.0f;
    for (int idx = tid; idx < CC * CC; idx += 256) {
        const int i = idx >> 5;
        const int k = idx & 31;
        if (i != k) {
            const float S = Tb[idx] * inv_n[k];
            sum += logf(0.5f + 0.5f * (diag_s[i] - S));
        }
    }
    #pragma unroll
    for (int off = 32; off > 0; off >>= 1) sum += __shfl_down(sum, off, 64);
    if ((tid & 63) == 0) wsum[tid >> 6] = sum;
    __syncthreads();
    if (tid == 0) out[b] = -(wsum[0] + wsum[1] + wsum[2] + wsum[3]);
}

extern "C" void kernel_launch(void* const* d_in, const int* in_sizes, int n_in,
                              void* d_out, int out_size, void* d_ws, size_t ws_size,
                              hipStream_t stream) {
    const float* pred   = (const float*)d_in[0];
    const int*   target = (const int*)d_in[1];
    float* out = (float*)d_out;
    float* P   = (float*)d_ws;                              // 1152*1056 floats
    float* Tn  = (float*)d_ws + (long)BB * NCHUNK * PART;   // 8448 floats

    jloss_mfma  <<<BB * NCHUNK, 256, 0, stream>>>(pred, target, P);
    jloss_reduce<<<(BB * PART) / 256, 256, 0, stream>>>(P, Tn);
    jloss_final <<<BB, 256, 0, stream>>>(Tn, out);
}